// Round 7
// baseline (323.858 us; speedup 1.0000x reference)
//
#include <hip/hip_runtime.h>
#include <hip/hip_bf16.h>

#define B_  32
#define N_  2048
#define M_  2048
#define D_  128

typedef __attribute__((ext_vector_type(4)))  float f32x4;
typedef __attribute__((ext_vector_type(16))) float f32x16;
typedef __attribute__((ext_vector_type(8)))  short bf16x8;

// log2(e) / sqrt(128): softmax in exp2 domain; folded into Q's bf16 cast.
static constexpr float SCALE2 = 1.4426950408889634f / 11.313708498984761f;

__device__ __forceinline__ unsigned short f2bf(float x) {
  union { float f; unsigned u; } c; c.f = x;
  unsigned u = c.u;
  return (unsigned short)((u + 0x7FFFu + ((u >> 16) & 1u)) >> 16);  // RNE
}

__device__ __forceinline__ unsigned pk2bf(float a, float b) {
  float2 f2; f2.x = a; f2.y = b;
  __hip_bfloat162 h = __float22bfloat162_rn(f2);   // v_cvt_pk_bf16_f32
  union { __hip_bfloat162 h; unsigned u; } c; c.h = h;
  return c.u;
}

// async global->LDS, 16B per lane; LDS dest = wave-uniform base + lane*16
__device__ __forceinline__ void gl2lds16(const void* gp, void* lp) {
  __builtin_amdgcn_global_load_lds(
      (const __attribute__((address_space(1))) unsigned int*)gp,
      (__attribute__((address_space(3))) unsigned int*)lp, 16, 0, 0);
}

// ---------- prep: fp32 -> bf16 for Q (scale=SCALE2) and K (scale=1) ----------
__global__ __launch_bounds__(256) void cvt_qk_kernel(
    const float* __restrict__ Q, const float* __restrict__ K,
    unsigned short* __restrict__ Qb, unsigned short* __restrict__ Kb, int n4) {
  int i = blockIdx.x * 256 + threadIdx.x;
  if (i >= n4) return;
  const float* src = blockIdx.y ? K : Q;
  unsigned short* dst = blockIdx.y ? Kb : Qb;
  const float sc = blockIdx.y ? 1.0f : SCALE2;
  const float4 v = reinterpret_cast<const float4*>(src)[i];
  ushort4 o;
  o.x = f2bf(v.x * sc); o.y = f2bf(v.y * sc);
  o.z = f2bf(v.z * sc); o.w = f2bf(v.w * sc);
  reinterpret_cast<ushort4*>(dst)[i] = o;
}

// ---------- prep: V (b,m,d) fp32 -> Vt (b,d,m) bf16, folding vscale[m] ----------
__global__ __launch_bounds__(256) void transpose_v_kernel(
    const float* __restrict__ V, const float* __restrict__ vscale,
    unsigned short* __restrict__ Vt) {
  const int b = blockIdx.z;
  const int m0 = blockIdx.x * 64;
  const int d0 = blockIdx.y * 64;
  __shared__ float t[64][65];
  const int tid = threadIdx.x;
  const int r = tid >> 2;   // 0..63
  const int c = tid & 3;    // 0..3
  const float* src = V + ((size_t)b * M_ + (m0 + r)) * D_ + d0 + c * 16;
  #pragma unroll
  for (int i = 0; i < 4; ++i) {
    float4 v = reinterpret_cast<const float4*>(src)[i];
    t[r][c * 16 + i * 4 + 0] = v.x;
    t[r][c * 16 + i * 4 + 1] = v.y;
    t[r][c * 16 + i * 4 + 2] = v.z;
    t[r][c * 16 + i * 4 + 3] = v.w;
  }
  __syncthreads();
  const float* vs = vscale + (size_t)b * M_ + m0 + c * 16;
  ushort4 ob[4];
  #pragma unroll
  for (int i = 0; i < 4; ++i) {
    float4 s4 = reinterpret_cast<const float4*>(vs)[i];
    ob[i].x = f2bf(t[c * 16 + i * 4 + 0][r] * s4.x);
    ob[i].y = f2bf(t[c * 16 + i * 4 + 1][r] * s4.y);
    ob[i].z = f2bf(t[c * 16 + i * 4 + 2][r] * s4.z);
    ob[i].w = f2bf(t[c * 16 + i * 4 + 3][r] * s4.w);
  }
  ushort4* dst = reinterpret_cast<ushort4*>(
      Vt + ((size_t)b * D_ + d0 + r) * M_ + m0 + c * 16);
  #pragma unroll
  for (int i = 0; i < 4; ++i) dst[i] = ob[i];
}

// =====================  PATH A: P materialization  =====================

// P[b][n][m] = 2^(s2[n,m]-16) (bf16) + vscale[m] = 1/colsum
__global__ __launch_bounds__(256, 2) void qk_exp_kernel(
    const unsigned short* __restrict__ Qb, const unsigned short* __restrict__ Kb,
    unsigned short* __restrict__ P, float* __restrict__ vscale) {
  const int b    = blockIdx.y;
  const int wv   = threadIdx.x >> 6;
  const int lane = threadIdx.x & 63;
  const int l31  = lane & 31;
  const int h    = lane >> 5;
  const int mw   = blockIdx.x * 128 + wv * 32;

  __shared__ unsigned short qbuf[64 * 128];   // 16 KB

  bf16x8 kf[8];   // A-operand: A[row=m=l31][k=kc*16+h*8+j]
  {
    const unsigned short* Kr = Kb + ((size_t)b * M_ + mw + l31) * D_ + h * 8;
    #pragma unroll
    for (int kc = 0; kc < 8; ++kc)
      kf[kc] = *reinterpret_cast<const bf16x8*>(Kr + kc * 16);
  }

  const unsigned short* Qbb = Qb + (size_t)b * N_ * D_;
  float ps[16];
  #pragma unroll
  for (int r = 0; r < 16; ++r) ps[r] = 0.f;

  for (int nt = 0; nt < N_; nt += 64) {
    __syncthreads();
    #pragma unroll
    for (int i = 0; i < 4; ++i) {
      int s = (wv * 4 + i) * 64 + lane;
      int nloc = s >> 4, c = (s & 15) ^ (nloc & 15);
      gl2lds16(Qbb + (size_t)(nt + nloc) * D_ + c * 8,
               (char*)qbuf + (size_t)s * 16);
    }
    __syncthreads();

    f32x16 acc[2] = {{}, {}};
    #pragma unroll
    for (int kc = 0; kc < 8; ++kc) {
      #pragma unroll
      for (int ng = 0; ng < 2; ++ng) {
        int row = ng * 32 + l31;
        int cq = (kc * 2 + h) ^ (row & 15);
        bf16x8 qfr = *reinterpret_cast<const bf16x8*>(qbuf + row * 128 + cq * 8);
        acc[ng] = __builtin_amdgcn_mfma_f32_32x32x16_bf16(kf[kc], qfr, acc[ng], 0, 0, 0);
      }
    }
    #pragma unroll
    for (int ng = 0; ng < 2; ++ng) {
      float e[16];
      #pragma unroll
      for (int r = 0; r < 16; ++r) {
        e[r] = exp2f(acc[ng][r] - 16.f);
        ps[r] += e[r];
      }
      unsigned short* prow =
          P + ((size_t)b * N_ + nt + ng * 32 + l31) * M_ + mw + 4 * h;
      #pragma unroll
      for (int g = 0; g < 4; ++g) {
        uint2 w;
        w.x = pk2bf(e[4 * g + 0], e[4 * g + 1]);
        w.y = pk2bf(e[4 * g + 2], e[4 * g + 3]);
        *reinterpret_cast<uint2*>(prow + 8 * g) = w;
      }
    }
  }
  #pragma unroll
  for (int r = 0; r < 16; ++r) {
    ps[r] += __shfl_xor(ps[r], 1);
    ps[r] += __shfl_xor(ps[r], 2);
    ps[r] += __shfl_xor(ps[r], 4);
    ps[r] += __shfl_xor(ps[r], 8);
    ps[r] += __shfl_xor(ps[r], 16);
  }
  if (l31 == 0) {
    #pragma unroll
    for (int r = 0; r < 16; ++r)
      vscale[(size_t)b * M_ + mw + (r & 3) + 8 * (r >> 2) + 4 * h] = 1.0f / ps[r];
  }
}

// O = P * V'^T — streaming bf16 GEMM
__global__ __launch_bounds__(256, 3) void pv_gemm_kernel(
    const unsigned short* __restrict__ P, const unsigned short* __restrict__ Vt,
    float* __restrict__ out) {
  const int b    = blockIdx.y;
  const int nt0  = blockIdx.x * 64;
  const int wv   = threadIdx.x >> 6;
  const int lane = threadIdx.x & 63;
  const int l15  = lane & 15;
  const int quad = lane >> 4;
  const int wr   = wv >> 1;
  const int wc   = wv & 1;

  __shared__ unsigned short abuf[64 * 32];
  __shared__ unsigned short bbuf[128 * 32];

  f32x4 o[2][4];
  #pragma unroll
  for (int ng = 0; ng < 2; ++ng)
    #pragma unroll
    for (int dt = 0; dt < 4; ++dt) o[ng][dt] = (f32x4){0.f, 0.f, 0.f, 0.f};

  const unsigned short* Pbb = P + ((size_t)b * N_ + nt0) * M_;
  const unsigned short* Vbb = Vt + (size_t)b * D_ * M_;

  for (int m0 = 0; m0 < M_; m0 += 32) {
    __syncthreads();
    {
      int s = wv * 64 + lane;
      int row = s >> 2, c = (s & 3) ^ ((row >> 1) & 3);
      gl2lds16(Pbb + (size_t)row * M_ + m0 + c * 8, (char*)abuf + (size_t)s * 16);
    }
    #pragma unroll
    for (int i = 0; i < 2; ++i) {
      int s = (wv * 2 + i) * 64 + lane;
      int row = s >> 2, c = (s & 3) ^ ((row >> 1) & 3);
      gl2lds16(Vbb + (size_t)row * M_ + m0 + c * 8, (char*)bbuf + (size_t)s * 16);
    }
    __syncthreads();

    bf16x8 pa[2];
    #pragma unroll
    for (int ng = 0; ng < 2; ++ng) {
      int row = wr * 32 + ng * 16 + l15;
      int pos = quad ^ ((row >> 1) & 3);
      pa[ng] = *reinterpret_cast<const bf16x8*>(abuf + row * 32 + pos * 8);
    }
    #pragma unroll
    for (int dt = 0; dt < 4; ++dt) {
      int rd = wc * 64 + dt * 16 + l15;
      int pos = quad ^ ((rd >> 1) & 3);
      bf16x8 vb = *reinterpret_cast<const bf16x8*>(bbuf + rd * 32 + pos * 8);
      o[0][dt] = __builtin_amdgcn_mfma_f32_16x16x32_bf16(pa[0], vb, o[0][dt], 0, 0, 0);
      o[1][dt] = __builtin_amdgcn_mfma_f32_16x16x32_bf16(pa[1], vb, o[1][dt], 0, 0, 0);
    }
  }

  #pragma unroll
  for (int ng = 0; ng < 2; ++ng)
    #pragma unroll
    for (int dt = 0; dt < 4; ++dt)
      #pragma unroll
      for (int r = 0; r < 4; ++r)
        out[((size_t)b * N_ + nt0 + wr * 32 + ng * 16 + quad * 4 + r) * D_ +
            wc * 64 + dt * 16 + l15] = o[ng][dt][r];
}

// =====================  PATH B: fused (small workspace)  =====================

// vscale[m] = 2^-16 / sum_n 2^(s2-16). 128-thr blocks, wave owns 32m (K regs,
// each Q-frag LDS read feeds 2 MFMA). Single-buffer two-barrier staging.
__global__ __launch_bounds__(128, 4) void colstats_v2_kernel(
    const unsigned short* __restrict__ Qb, const unsigned short* __restrict__ Kb,
    float* __restrict__ vscale) {
  const int b    = blockIdx.y;
  const int wv   = threadIdx.x >> 6;   // 0..1
  const int lane = threadIdx.x & 63;
  const int l15  = lane & 15;
  const int quad = lane >> 4;
  const int mw   = blockIdx.x * 64 + wv * 32;

  __shared__ unsigned short qbuf[64 * 128];   // 16 KB; rows n, chunk c at pos c^(n&15)

  bf16x8 kf[2][4];   // B-operand: B[col=m=cg*16+l15][k=quad*8+j]
  #pragma unroll
  for (int cg = 0; cg < 2; ++cg) {
    const unsigned short* Kr =
        Kb + ((size_t)b * M_ + mw + cg * 16 + l15) * D_ + quad * 8;
    #pragma unroll
    for (int kc = 0; kc < 4; ++kc)
      kf[cg][kc] = *reinterpret_cast<const bf16x8*>(Kr + kc * 32);
  }

  const unsigned short* Qbb = Qb + (size_t)b * N_ * D_;
  float psum[2] = {0.f, 0.f};

  for (int nt = 0; nt < N_; nt += 64) {
    __syncthreads();                           // previous-tile reads done
    #pragma unroll
    for (int i = 0; i < 8; ++i) {
      int s = (wv * 8 + i) * 64 + lane;        // 16B slot 0..1023
      int nloc = s >> 4, c = (s & 15) ^ (nloc & 15);
      gl2lds16(Qbb + (size_t)(nt + nloc) * D_ + c * 8,
               (char*)qbuf + (size_t)s * 16);
    }
    __syncthreads();                           // staging visible
    #pragma unroll
    for (int ng = 0; ng < 4; ++ng) {
      const int n_l = ng * 16 + l15;
      f32x4 acc[2] = {{0.f,0.f,0.f,0.f}, {0.f,0.f,0.f,0.f}};
      #pragma unroll
      for (int kc = 0; kc < 4; ++kc) {
        int c = (kc * 4 + quad) ^ (n_l & 15);
        bf16x8 af = *reinterpret_cast<const bf16x8*>(qbuf + n_l * 128 + c * 8);
        acc[0] = __builtin_amdgcn_mfma_f32_16x16x32_bf16(af, kf[0][kc], acc[0], 0, 0, 0);
        acc[1] = __builtin_amdgcn_mfma_f32_16x16x32_bf16(af, kf[1][kc], acc[1], 0, 0, 0);
      }
      #pragma unroll
      for (int cg = 0; cg < 2; ++cg)
        psum[cg] += exp2f(acc[cg][0] - 16.f) + exp2f(acc[cg][1] - 16.f) +
                    exp2f(acc[cg][2] - 16.f) + exp2f(acc[cg][3] - 16.f);
    }
  }
  #pragma unroll
  for (int cg = 0; cg < 2; ++cg) {
    psum[cg] += __shfl_xor(psum[cg], 16);
    psum[cg] += __shfl_xor(psum[cg], 32);
  }
  if (quad == 0) {
    vscale[(size_t)b * M_ + mw + l15]      = 0x1p-16f / psum[0];
    vscale[(size_t)b * M_ + mw + 16 + l15] = 0x1p-16f / psum[1];
  }
}

// O[n,d] = sum_m 2^s2 * V'[d,m]. 128-thr blocks, wave owns 32n: each K-frag and
// V-frag LDS read feeds 2 MFMA (n-groups). S^T trick for packed b64 P stores.
__global__ __launch_bounds__(128, 3) void attn_v2_kernel(
    const unsigned short* __restrict__ Qb, const unsigned short* __restrict__ Kb,
    const unsigned short* __restrict__ Vt, float* __restrict__ out) {
  const int b    = blockIdx.y;
  const int wv   = threadIdx.x >> 6;   // 0..1
  const int lane = threadIdx.x & 63;
  const int l15  = lane & 15;
  const int quad = lane >> 4;
  const int nq   = blockIdx.x * 64 + wv * 32;

  __shared__ unsigned short kbuf[32 * 128];   // 8 KB: rows m (256B, 16 chunks)
  __shared__ unsigned short vbuf[128 * 32];   // 8 KB: rows d (64B, 4 chunks)
  __shared__ unsigned short pbuf[2][32 * 40]; // per-wave P^T [n][m], stride 80B

  // Q B-operand: B[col=n=ng*16+l15][k=quad*8+j] — loop invariant
  bf16x8 qf[2][4];
  #pragma unroll
  for (int ng = 0; ng < 2; ++ng) {
    const unsigned short* Qr =
        Qb + ((size_t)b * N_ + nq + ng * 16 + l15) * D_ + quad * 8;
    #pragma unroll
    for (int kc = 0; kc < 4; ++kc)
      qf[ng][kc] = *reinterpret_cast<const bf16x8*>(Qr + kc * 32);
  }

  f32x4 o[2][8];
  #pragma unroll
  for (int ng = 0; ng < 2; ++ng)
    #pragma unroll
    for (int dt = 0; dt < 8; ++dt) o[ng][dt] = (f32x4){0.f, 0.f, 0.f, 0.f};

  const unsigned short* Kbb = Kb + (size_t)b * M_ * D_;
  const unsigned short* Vbb = Vt + (size_t)b * D_ * M_;
  unsigned short* pw = pbuf[wv];

  for (int m0 = 0; m0 < M_; m0 += 32) {
    __syncthreads();                          // previous-chunk reads done
    #pragma unroll
    for (int i = 0; i < 4; ++i) {
      int s = (wv * 4 + i) * 64 + lane;       // 16B slot 0..511
      int mloc = s >> 4, ck = (s & 15) ^ (mloc & 15);
      gl2lds16(Kbb + (size_t)(m0 + mloc) * D_ + ck * 8,
               (char*)kbuf + (size_t)s * 16);
      int dloc = s >> 2, cv = (s & 3) ^ ((dloc >> 1) & 3);
      gl2lds16(Vbb + (size_t)dloc * M_ + m0 + cv * 8,
               (char*)vbuf + (size_t)s * 16);
    }
    __syncthreads();                          // staging visible

    // QK^T (S^T): sacc[cg][ng]: row m = cg*16+quad*4+r, col n = ng*16+l15
    f32x4 sacc[2][2] = {{{0.f,0.f,0.f,0.f},{0.f,0.f,0.f,0.f}},
                        {{0.f,0.f,0.f,0.f},{0.f,0.f,0.f,0.f}}};
    #pragma unroll
    for (int kc = 0; kc < 4; ++kc) {
      #pragma unroll
      for (int cg = 0; cg < 2; ++cg) {
        int ck = (kc * 4 + quad) ^ l15;       // (m&15)==l15
        bf16x8 kfr = *reinterpret_cast<const bf16x8*>(kbuf + (cg * 16 + l15) * 128 + ck * 8);
        sacc[cg][0] = __builtin_amdgcn_mfma_f32_16x16x32_bf16(kfr, qf[0][kc], sacc[cg][0], 0, 0, 0);
        sacc[cg][1] = __builtin_amdgcn_mfma_f32_16x16x32_bf16(kfr, qf[1][kc], sacc[cg][1], 0, 0, 0);
      }
    }
    // P stores: packed b64 of 4 consecutive m per (cg, ng)
    #pragma unroll
    for (int cg = 0; cg < 2; ++cg)
      #pragma unroll
      for (int ng = 0; ng < 2; ++ng) {
        uint2 w;
        w.x = pk2bf(exp2f(sacc[cg][ng][0]), exp2f(sacc[cg][ng][1]));
        w.y = pk2bf(exp2f(sacc[cg][ng][2]), exp2f(sacc[cg][ng][3]));
        *reinterpret_cast<uint2*>(pw + (ng * 16 + l15) * 40 + cg * 16 + quad * 4) = w;
      }
    // P A-frags: A[row=n][k=m=quad*8+j] (same-wave LDS RAW; lgkmcnt ordered)
    bf16x8 pa[2];
    #pragma unroll
    for (int ng = 0; ng < 2; ++ng)
      pa[ng] = *reinterpret_cast<const bf16x8*>(pw + (ng * 16 + l15) * 40 + quad * 8);
    // PV: each V-frag read feeds both n-groups
    #pragma unroll
    for (int dt = 0; dt < 8; ++dt) {
      const int d = dt * 16 + l15;
      int pos = quad ^ ((d >> 1) & 3);
      bf16x8 vfr = *reinterpret_cast<const bf16x8*>(vbuf + d * 32 + pos * 8);
      o[0][dt] = __builtin_amdgcn_mfma_f32_16x16x32_bf16(pa[0], vfr, o[0][dt], 0, 0, 0);
      o[1][dt] = __builtin_amdgcn_mfma_f32_16x16x32_bf16(pa[1], vfr, o[1][dt], 0, 0, 0);
    }
  }

  // epilogue: o[ng][dt][r] = O[nq + ng*16 + quad*4 + r][dt*16 + l15]
  #pragma unroll
  for (int ng = 0; ng < 2; ++ng)
    #pragma unroll
    for (int dt = 0; dt < 8; ++dt)
      #pragma unroll
      for (int r = 0; r < 4; ++r)
        out[((size_t)b * N_ + nq + ng * 16 + quad * 4 + r) * D_ + dt * 16 + l15] =
            o[ng][dt][r];
}

extern "C" void kernel_launch(void* const* d_in, const int* in_sizes, int n_in,
                              void* d_out, int out_size, void* d_ws, size_t ws_size,
                              hipStream_t stream) {
  const float* Q = (const float*)d_in[0];
  const float* K = (const float*)d_in[1];
  const float* V = (const float*)d_in[2];
  float* out = (float*)d_out;

  const size_t elems = (size_t)B_ * N_ * D_;   // 8,388,608 per tensor
  unsigned short* Qb = (unsigned short*)d_ws;                  // 16 MB
  unsigned short* Kb = Qb + elems;                             // 16 MB
  unsigned short* Vt = Kb + elems;                             // 16 MB
  float* vscale = (float*)(Vt + elems);                        // 256 KB
  unsigned short* P = (unsigned short*)(vscale + (size_t)B_ * M_);

  const size_t needA = 3 * elems * 2 + (size_t)B_ * M_ * 4 +
                       (size_t)B_ * N_ * M_ * 2;               // ~304.3 MB

  const int n4 = (int)(elems / 4);
  cvt_qk_kernel<<<dim3(n4 / 256, 2), 256, 0, stream>>>(Q, K, Qb, Kb, n4);

  if (ws_size >= needA) {
    // Path A: materialize P (bf16), then pure streaming GEMM
    qk_exp_kernel<<<dim3(M_ / 128, B_), 256, 0, stream>>>(Qb, Kb, P, vscale);
    transpose_v_kernel<<<dim3(M_ / 64, D_ / 64, B_), 256, 0, stream>>>(V, vscale, Vt);
    pv_gemm_kernel<<<dim3(N_ / 64, B_), 256, 0, stream>>>(P, Vt, out);
  } else {
    // Path B: fused, small workspace (~48.3 MB)
    colstats_v2_kernel<<<dim3(M_ / 64, B_), 128, 0, stream>>>(Qb, Kb, vscale);
    transpose_v_kernel<<<dim3(M_ / 64, D_ / 64, B_), 256, 0, stream>>>(V, vscale, Vt);
    attn_v2_kernel<<<dim3(N_ / 64, B_), 128, 0, stream>>>(Qb, Kb, Vt, out);
  }
}

// Round 8
// 309.473 us; speedup vs baseline: 1.0465x; 1.0465x over previous
//
#include <hip/hip_runtime.h>
#include <hip/hip_bf16.h>

#define B_  32
#define N_  2048
#define M_  2048
#define D_  128

typedef __attribute__((ext_vector_type(4)))  float f32x4;
typedef __attribute__((ext_vector_type(8)))  short bf16x8;

// log2(e) / sqrt(128): softmax in exp2 domain; folded into Q's bf16 cast.
static constexpr float SCALE2 = 1.4426950408889634f / 11.313708498984761f;

__device__ __forceinline__ unsigned short f2bf(float x) {
  union { float f; unsigned u; } c; c.f = x;
  unsigned u = c.u;
  return (unsigned short)((u + 0x7FFFu + ((u >> 16) & 1u)) >> 16);  // RNE
}

__device__ __forceinline__ unsigned pk2bf(float a, float b) {
  float2 f2; f2.x = a; f2.y = b;
  __hip_bfloat162 h = __float22bfloat162_rn(f2);   // v_cvt_pk_bf16_f32
  union { __hip_bfloat162 h; unsigned u; } c; c.h = h;
  return c.u;
}

// async global->LDS, 16B per lane; LDS dest = wave-uniform base + lane*16
__device__ __forceinline__ void gl2lds16(const void* gp, void* lp) {
  __builtin_amdgcn_global_load_lds(
      (const __attribute__((address_space(1))) unsigned int*)gp,
      (__attribute__((address_space(3))) unsigned int*)lp, 16, 0, 0);
}

// ---------- prep: fp32 -> bf16 for Q (scale=SCALE2) / K (scale=1); zero colsum ----------
__global__ __launch_bounds__(256) void cvt_qk_kernel(
    const float* __restrict__ Q, const float* __restrict__ K,
    unsigned short* __restrict__ Qb, unsigned short* __restrict__ Kb,
    float* __restrict__ colsum, int n4) {
  int i = blockIdx.x * 256 + threadIdx.x;
  if (i >= n4) return;
  if (blockIdx.y == 0 && i < (B_ * M_) / 4)
    reinterpret_cast<float4*>(colsum)[i] = make_float4(0.f, 0.f, 0.f, 0.f);
  const float* src = blockIdx.y ? K : Q;
  unsigned short* dst = blockIdx.y ? Kb : Qb;
  const float sc = blockIdx.y ? 1.0f : SCALE2;
  const float4 v = reinterpret_cast<const float4*>(src)[i];
  ushort4 o;
  o.x = f2bf(v.x * sc); o.y = f2bf(v.y * sc);
  o.z = f2bf(v.z * sc); o.w = f2bf(v.w * sc);
  reinterpret_cast<ushort4*>(dst)[i] = o;
}

// ---------- pass 1: colsum[b][m] += sum_{n in stripe} 2^(s2[n,m]-16) ----------
// grid (M/64, 4 n-stripes, B), 128 thr (2 waves); wave owns 32 m (K-frags in regs,
// each Q-frag LDS read feeds 2 MFMA). Single-buffer two-barrier staging.
__global__ __launch_bounds__(128, 4) void colstats_v3_kernel(
    const unsigned short* __restrict__ Qb, const unsigned short* __restrict__ Kb,
    float* __restrict__ colsum) {
  const int b    = blockIdx.z;
  const int wv   = threadIdx.x >> 6;   // 0..1
  const int lane = threadIdx.x & 63;
  const int l15  = lane & 15;
  const int quad = lane >> 4;
  const int mw   = blockIdx.x * 64 + wv * 32;
  const int nbase = blockIdx.y * (N_ / 4);

  __shared__ unsigned short qbuf[64 * 128];   // 16 KB; rows n, chunk c at pos c^(n&15)

  bf16x8 kf[2][4];   // B-operand: B[col=m=cg*16+l15][k=quad*8+j]
  #pragma unroll
  for (int cg = 0; cg < 2; ++cg) {
    const unsigned short* Kr =
        Kb + ((size_t)b * M_ + mw + cg * 16 + l15) * D_ + quad * 8;
    #pragma unroll
    for (int kc = 0; kc < 4; ++kc)
      kf[cg][kc] = *reinterpret_cast<const bf16x8*>(Kr + kc * 32);
  }

  const unsigned short* Qbb = Qb + (size_t)b * N_ * D_;
  float psum[2] = {0.f, 0.f};

  for (int it = 0; it < (N_ / 4) / 64; ++it) {
    const int nt = nbase + it * 64;
    __syncthreads();                           // previous-tile reads done
    #pragma unroll
    for (int i = 0; i < 8; ++i) {
      int s = (wv * 8 + i) * 64 + lane;        // 16B slot 0..1023
      int nloc = s >> 4, c = (s & 15) ^ (nloc & 15);
      gl2lds16(Qbb + (size_t)(nt + nloc) * D_ + c * 8,
               (char*)qbuf + (size_t)s * 16);
    }
    __syncthreads();                           // staging visible
    #pragma unroll
    for (int ng = 0; ng < 4; ++ng) {
      const int n_l = ng * 16 + l15;
      f32x4 acc[2] = {{0.f,0.f,0.f,0.f}, {0.f,0.f,0.f,0.f}};
      #pragma unroll
      for (int kc = 0; kc < 4; ++kc) {
        int c = (kc * 4 + quad) ^ (n_l & 15);
        bf16x8 af = *reinterpret_cast<const bf16x8*>(qbuf + n_l * 128 + c * 8);
        acc[0] = __builtin_amdgcn_mfma_f32_16x16x32_bf16(af, kf[0][kc], acc[0], 0, 0, 0);
        acc[1] = __builtin_amdgcn_mfma_f32_16x16x32_bf16(af, kf[1][kc], acc[1], 0, 0, 0);
      }
      #pragma unroll
      for (int cg = 0; cg < 2; ++cg)
        psum[cg] += exp2f(acc[cg][0] - 16.f) + exp2f(acc[cg][1] - 16.f) +
                    exp2f(acc[cg][2] - 16.f) + exp2f(acc[cg][3] - 16.f);
    }
  }
  #pragma unroll
  for (int cg = 0; cg < 2; ++cg) {
    psum[cg] += __shfl_xor(psum[cg], 16);
    psum[cg] += __shfl_xor(psum[cg], 32);
  }
  if (quad == 0) {
    atomicAdd(colsum + (size_t)b * M_ + mw + l15,      psum[0]);
    atomicAdd(colsum + (size_t)b * M_ + mw + 16 + l15, psum[1]);
  }
}

// ---------- prep: V (b,m,d) fp32 -> Vt (b,d,m) bf16, folding 2^-16/colsum[m] ----------
__global__ __launch_bounds__(256) void transpose_v_kernel(
    const float* __restrict__ V, const float* __restrict__ colsum,
    unsigned short* __restrict__ Vt) {
  const int b = blockIdx.z;
  const int m0 = blockIdx.x * 64;
  const int d0 = blockIdx.y * 64;
  __shared__ float t[64][65];
  const int tid = threadIdx.x;
  const int r = tid >> 2;   // 0..63
  const int c = tid & 3;    // 0..3
  const float* src = V + ((size_t)b * M_ + (m0 + r)) * D_ + d0 + c * 16;
  #pragma unroll
  for (int i = 0; i < 4; ++i) {
    float4 v = reinterpret_cast<const float4*>(src)[i];
    t[r][c * 16 + i * 4 + 0] = v.x;
    t[r][c * 16 + i * 4 + 1] = v.y;
    t[r][c * 16 + i * 4 + 2] = v.z;
    t[r][c * 16 + i * 4 + 3] = v.w;
  }
  __syncthreads();
  const float* cs = colsum + (size_t)b * M_ + m0 + c * 16;
  ushort4 ob[4];
  #pragma unroll
  for (int i = 0; i < 4; ++i) {
    float4 s4 = reinterpret_cast<const float4*>(cs)[i];
    float sx = 0x1p-16f / s4.x, sy = 0x1p-16f / s4.y;
    float sz = 0x1p-16f / s4.z, sw = 0x1p-16f / s4.w;
    ob[i].x = f2bf(t[c * 16 + i * 4 + 0][r] * sx);
    ob[i].y = f2bf(t[c * 16 + i * 4 + 1][r] * sy);
    ob[i].z = f2bf(t[c * 16 + i * 4 + 2][r] * sz);
    ob[i].w = f2bf(t[c * 16 + i * 4 + 3][r] * sw);
  }
  ushort4* dst = reinterpret_cast<ushort4*>(
      Vt + ((size_t)b * D_ + d0 + r) * M_ + m0 + c * 16);
  #pragma unroll
  for (int i = 0; i < 4; ++i) dst[i] = ob[i];
}

// ---------- pass 2: O[n,d] = sum_m 2^s2 * V'[d,m] ----------
// grid (N/64, B), 256 thr = 4 waves: {m-half} x {n-set}. Each wave: 32n, half the
// m-range in 32-chunks (32 iters, half the barriers of R7). Per-wave LDS traffic
// unchanged (each K/V frag read feeds 2 MFMA). Partial-O combine via LDS reuse.
__global__ __launch_bounds__(256, 3) void attn_v3_kernel(
    const unsigned short* __restrict__ Qb, const unsigned short* __restrict__ Kb,
    const unsigned short* __restrict__ Vt, float* __restrict__ out) {
  const int b    = blockIdx.y;
  const int wv   = threadIdx.x >> 6;   // 0..3
  const int lane = threadIdx.x & 63;
  const int l15  = lane & 15;
  const int quad = lane >> 4;
  const int nset = wv & 1;
  const int mh   = wv >> 1;            // m-half: 0 -> [0,1024), 1 -> [1024,2048)
  const int nq   = blockIdx.x * 64 + nset * 32;

  // smem layout: [kbuf(2 x 8KB)][vbuf(2 x 8KB)][pbuf(4 x 2.5KB)] = 42 KB
  // epilogue reuses first 32 KB (kbuf+vbuf) as the f32 O-exchange buffer.
  __shared__ unsigned short smem[21504];
  unsigned short* kb = smem + mh * 4096;           // 32m x 128d rows (256B, 16 chunks)
  unsigned short* vb = smem + 8192 + mh * 4096;    // 128d x 32m rows (64B, 4 chunks)
  unsigned short* pw = smem + 16384 + wv * 1280;   // per-wave P^T [n][m], stride 40 u16

  // Q B-operand: B[col=n=ng*16+l15][k=quad*8+j] — loop invariant
  bf16x8 qf[2][4];
  #pragma unroll
  for (int ng = 0; ng < 2; ++ng) {
    const unsigned short* Qr =
        Qb + ((size_t)b * N_ + nq + ng * 16 + l15) * D_ + quad * 8;
    #pragma unroll
    for (int kc = 0; kc < 4; ++kc)
      qf[ng][kc] = *reinterpret_cast<const bf16x8*>(Qr + kc * 32);
  }

  f32x4 o[2][8];
  #pragma unroll
  for (int ng = 0; ng < 2; ++ng)
    #pragma unroll
    for (int dt = 0; dt < 8; ++dt) o[ng][dt] = (f32x4){0.f, 0.f, 0.f, 0.f};

  const unsigned short* Kbb = Kb + (size_t)b * M_ * D_;
  const unsigned short* Vbb = Vt + (size_t)b * D_ * M_;

  for (int it = 0; it < 32; ++it) {
    const int m0 = mh * (M_ / 2) + it * 32;
    __syncthreads();                          // previous-chunk reads done (all waves)
    // wave-pair mh stages its own K/V tiles: 2 waves x 4 instr each per buffer
    #pragma unroll
    for (int i = 0; i < 4; ++i) {
      int s = ((nset * 4 + i)) * 64 + lane;   // 16B slot 0..511 within this half
      int mloc = s >> 4, ck = (s & 15) ^ (mloc & 15);
      gl2lds16(Kbb + (size_t)(m0 + mloc) * D_ + ck * 8,
               (char*)kb + (size_t)s * 16);
      int dloc = s >> 2, cv = (s & 3) ^ ((dloc >> 1) & 3);
      gl2lds16(Vbb + (size_t)dloc * M_ + m0 + cv * 8,
               (char*)vb + (size_t)s * 16);
    }
    __syncthreads();                          // staging visible

    // QK^T (S^T): sacc[cg][ng]: row m = cg*16+quad*4+r, col n = ng*16+l15
    f32x4 sacc[2][2] = {{{0.f,0.f,0.f,0.f},{0.f,0.f,0.f,0.f}},
                        {{0.f,0.f,0.f,0.f},{0.f,0.f,0.f,0.f}}};
    #pragma unroll
    for (int kc = 0; kc < 4; ++kc) {
      #pragma unroll
      for (int cg = 0; cg < 2; ++cg) {
        int ck = (kc * 4 + quad) ^ l15;       // (m&15)==l15
        bf16x8 kfr = *reinterpret_cast<const bf16x8*>(kb + (cg * 16 + l15) * 128 + ck * 8);
        sacc[cg][0] = __builtin_amdgcn_mfma_f32_16x16x32_bf16(kfr, qf[0][kc], sacc[cg][0], 0, 0, 0);
        sacc[cg][1] = __builtin_amdgcn_mfma_f32_16x16x32_bf16(kfr, qf[1][kc], sacc[cg][1], 0, 0, 0);
      }
    }
    // P stores: packed b64 of 4 consecutive m per (cg, ng)
    #pragma unroll
    for (int cg = 0; cg < 2; ++cg)
      #pragma unroll
      for (int ng = 0; ng < 2; ++ng) {
        uint2 w;
        w.x = pk2bf(exp2f(sacc[cg][ng][0]), exp2f(sacc[cg][ng][1]));
        w.y = pk2bf(exp2f(sacc[cg][ng][2]), exp2f(sacc[cg][ng][3]));
        *reinterpret_cast<uint2*>(pw + (ng * 16 + l15) * 40 + cg * 16 + quad * 4) = w;
      }
    // P A-frags: A[row=n][k=m=quad*8+j] (same-wave LDS RAW; lgkmcnt ordered)
    bf16x8 pa[2];
    #pragma unroll
    for (int ng = 0; ng < 2; ++ng)
      pa[ng] = *reinterpret_cast<const bf16x8*>(pw + (ng * 16 + l15) * 40 + quad * 8);
    // PV: each V-frag read feeds both n-groups
    #pragma unroll
    for (int dt = 0; dt < 8; ++dt) {
      const int d = dt * 16 + l15;
      int pos = quad ^ ((d >> 1) & 3);
      bf16x8 vfr = *reinterpret_cast<const bf16x8*>(vb + d * 32 + pos * 8);
      o[0][dt] = __builtin_amdgcn_mfma_f32_16x16x32_bf16(pa[0], vfr, o[0][dt], 0, 0, 0);
      o[1][dt] = __builtin_amdgcn_mfma_f32_16x16x32_bf16(pa[1], vfr, o[1][dt], 0, 0, 0);
    }
  }

  // combine m-halves through LDS (reuse staging region), then write out
  __syncthreads();                            // all K/V reads done before overwrite
  float* xch = (float*)smem;                  // 2 x (32n x 128d) f32 = 32 KB
  if (mh == 1) {
    #pragma unroll
    for (int ng = 0; ng < 2; ++ng)
      #pragma unroll
      for (int dt = 0; dt < 8; ++dt)
        #pragma unroll
        for (int r = 0; r < 4; ++r)
          xch[nset * 4096 + (ng * 16 + quad * 4 + r) * 128 + dt * 16 + l15] =
              o[ng][dt][r];
  }
  __syncthreads();
  if (mh == 0) {
    #pragma unroll
    for (int ng = 0; ng < 2; ++ng)
      #pragma unroll
      for (int dt = 0; dt < 8; ++dt)
        #pragma unroll
        for (int r = 0; r < 4; ++r) {
          float v = o[ng][dt][r] +
                    xch[nset * 4096 + (ng * 16 + quad * 4 + r) * 128 + dt * 16 + l15];
          out[((size_t)b * N_ + nq + ng * 16 + quad * 4 + r) * D_ + dt * 16 + l15] = v;
        }
  }
}

extern "C" void kernel_launch(void* const* d_in, const int* in_sizes, int n_in,
                              void* d_out, int out_size, void* d_ws, size_t ws_size,
                              hipStream_t stream) {
  const float* Q = (const float*)d_in[0];
  const float* K = (const float*)d_in[1];
  const float* V = (const float*)d_in[2];
  float* out = (float*)d_out;

  const size_t elems = (size_t)B_ * N_ * D_;   // 8,388,608 per tensor
  unsigned short* Qb = (unsigned short*)d_ws;                  // 16 MB
  unsigned short* Kb = Qb + elems;                             // 16 MB
  unsigned short* Vt = Kb + elems;                             // 16 MB
  float* colsum = (float*)(Vt + elems);                        // 256 KB
  // total ws use ~= 48.3 MB (proven safe)

  const int n4 = (int)(elems / 4);
  cvt_qk_kernel<<<dim3(n4 / 256, 2), 256, 0, stream>>>(Q, K, Qb, Kb, colsum, n4);
  colstats_v3_kernel<<<dim3(M_ / 64, 4, B_), 128, 0, stream>>>(Qb, Kb, colsum);
  transpose_v_kernel<<<dim3(M_ / 64, D_ / 64, B_), 256, 0, stream>>>(V, colsum, Vt);
  attn_v3_kernel<<<dim3(N_ / 64, B_), 256, 0, stream>>>(Qb, Kb, Vt, out);
}

// Round 9
// 265.871 us; speedup vs baseline: 1.2181x; 1.1640x over previous
//
#include <hip/hip_runtime.h>
#include <hip/hip_bf16.h>

#define B_  32
#define N_  2048
#define M_  2048
#define D_  128

typedef __attribute__((ext_vector_type(4)))  float f32x4;
typedef __attribute__((ext_vector_type(8)))  short bf16x8;

// log2(e) / sqrt(128): softmax in exp2 domain; folded into Q's bf16 cast.
static constexpr float SCALE2 = 1.4426950408889634f / 11.313708498984761f;

__device__ __forceinline__ unsigned short f2bf(float x) {
  union { float f; unsigned u; } c; c.f = x;
  unsigned u = c.u;
  return (unsigned short)((u + 0x7FFFu + ((u >> 16) & 1u)) >> 16);  // RNE
}

__device__ __forceinline__ unsigned pk2bf(float a, float b) {
  float2 f2; f2.x = a; f2.y = b;
  __hip_bfloat162 h = __float22bfloat162_rn(f2);   // v_cvt_pk_bf16_f32
  union { __hip_bfloat162 h; unsigned u; } c; c.h = h;
  return c.u;
}

// raw v_exp_f32 (2^x) — skips ocml edge-case wrapper VALU
__device__ __forceinline__ float fexp2(float x) {
#if __has_builtin(__builtin_amdgcn_exp2f)
  return __builtin_amdgcn_exp2f(x);
#else
  float r; asm("v_exp_f32 %0, %1" : "=v"(r) : "v"(x)); return r;
#endif
}

// async global->LDS, 16B per lane; LDS dest = wave-uniform base + lane*16
__device__ __forceinline__ void gl2lds16(const void* gp, void* lp) {
  __builtin_amdgcn_global_load_lds(
      (const __attribute__((address_space(1))) unsigned int*)gp,
      (__attribute__((address_space(3))) unsigned int*)lp, 16, 0, 0);
}

// ---------- prep: fp32 -> bf16 for Q (scale=SCALE2) / K (scale=1); zero colsum ----------
__global__ __launch_bounds__(256) void cvt_qk_kernel(
    const float* __restrict__ Q, const float* __restrict__ K,
    unsigned short* __restrict__ Qb, unsigned short* __restrict__ Kb,
    float* __restrict__ colsum, int n4) {
  int i = blockIdx.x * 256 + threadIdx.x;
  if (i >= n4) return;
  if (blockIdx.y == 0 && i < (B_ * M_) / 4)
    reinterpret_cast<float4*>(colsum)[i] = make_float4(0.f, 0.f, 0.f, 0.f);
  const float* src = blockIdx.y ? K : Q;
  unsigned short* dst = blockIdx.y ? Kb : Qb;
  const float sc = blockIdx.y ? 1.0f : SCALE2;
  const float4 v = reinterpret_cast<const float4*>(src)[i];
  ushort4 o;
  o.x = f2bf(v.x * sc); o.y = f2bf(v.y * sc);
  o.z = f2bf(v.z * sc); o.w = f2bf(v.w * sc);
  reinterpret_cast<ushort4*>(dst)[i] = o;
}

// ---------- pass 1: colsum[b][m] += sum_{n in stripe} 2^(s2[n,m]-16) ----------
// grid (M/64, 4 n-stripes, B), 128 thr (2 waves); wave owns 32 m (K-frags in regs).
// All LDS read addresses hoisted (base + constant offset); DMA via running ptrs.
__global__ __launch_bounds__(128, 4) void colstats_v4_kernel(
    const unsigned short* __restrict__ Qb, const unsigned short* __restrict__ Kb,
    float* __restrict__ colsum) {
  const int b    = blockIdx.z;
  const int lane = threadIdx.x & 63;
  const int l15  = lane & 15;
  const int quad = lane >> 4;
  const int mw   = blockIdx.x * 64 + (threadIdx.x >> 6) * 32;
  const int nbase = blockIdx.y * (N_ / 4);

  __shared__ unsigned short qbuf[64 * 128];   // 16 KB; rows n, chunk c at pos c^(n&15)

  bf16x8 kf[2][4];   // B-operand: B[col=m=cg*16+l15][k=quad*8+j]
  #pragma unroll
  for (int cg = 0; cg < 2; ++cg) {
    const unsigned short* Kr =
        Kb + ((size_t)b * M_ + mw + cg * 16 + l15) * D_ + quad * 8;
    #pragma unroll
    for (int kc = 0; kc < 4; ++kc)
      kf[cg][kc] = *reinterpret_cast<const bf16x8*>(Kr + kc * 32);
  }

  // hoisted LDS read bases: q addr = (ng*16+l15)*128 + ((kc*4+quad)^l15)*8 [+ng*2048]
  const unsigned short* pq[4];
  #pragma unroll
  for (int kc = 0; kc < 4; ++kc)
    pq[kc] = qbuf + l15 * 128 + (((kc * 4 + quad) ^ l15) * 8);

  // running DMA source pointers (8 slots/thread), dest constant per thread
  const unsigned short* qg[8];
  unsigned short* ql[8];
  #pragma unroll
  for (int i = 0; i < 8; ++i) {
    int s = i * 128 + threadIdx.x;              // 16B slot 0..1023
    int nloc = s >> 4, c = (s & 15) ^ (nloc & 15);
    qg[i] = Qb + ((size_t)b * N_ + nbase + nloc) * D_ + c * 8;
    ql[i] = qbuf + (size_t)s * 8;               // s*16 bytes
  }

  float psum[2] = {0.f, 0.f};

  for (int it = 0; it < (N_ / 4) / 64; ++it) {
    __syncthreads();                            // previous-tile reads done
    #pragma unroll
    for (int i = 0; i < 8; ++i) {
      gl2lds16(qg[i], ql[i]);
      qg[i] += 64 * D_;
    }
    __syncthreads();                            // staging visible
    #pragma unroll
    for (int ng = 0; ng < 4; ++ng) {
      f32x4 acc[2] = {{0.f,0.f,0.f,0.f}, {0.f,0.f,0.f,0.f}};
      #pragma unroll
      for (int kc = 0; kc < 4; ++kc) {
        bf16x8 af = *reinterpret_cast<const bf16x8*>(pq[kc] + ng * 2048);
        acc[0] = __builtin_amdgcn_mfma_f32_16x16x32_bf16(af, kf[0][kc], acc[0], 0, 0, 0);
        acc[1] = __builtin_amdgcn_mfma_f32_16x16x32_bf16(af, kf[1][kc], acc[1], 0, 0, 0);
      }
      #pragma unroll
      for (int cg = 0; cg < 2; ++cg)
        psum[cg] += fexp2(acc[cg][0] - 16.f) + fexp2(acc[cg][1] - 16.f) +
                    fexp2(acc[cg][2] - 16.f) + fexp2(acc[cg][3] - 16.f);
    }
  }
  #pragma unroll
  for (int cg = 0; cg < 2; ++cg) {
    psum[cg] += __shfl_xor(psum[cg], 16);
    psum[cg] += __shfl_xor(psum[cg], 32);
  }
  if (quad == 0) {
    atomicAdd(colsum + (size_t)b * M_ + mw + l15,      psum[0]);
    atomicAdd(colsum + (size_t)b * M_ + mw + 16 + l15, psum[1]);
  }
}

// ---------- prep: V (b,m,d) fp32 -> Vt (b,d,m) bf16, folding 2^-16/colsum[m] ----------
__global__ __launch_bounds__(256) void transpose_v_kernel(
    const float* __restrict__ V, const float* __restrict__ colsum,
    unsigned short* __restrict__ Vt) {
  const int b = blockIdx.z;
  const int m0 = blockIdx.x * 64;
  const int d0 = blockIdx.y * 64;
  __shared__ float t[64][65];
  const int tid = threadIdx.x;
  const int r = tid >> 2;   // 0..63
  const int c = tid & 3;    // 0..3
  const float* src = V + ((size_t)b * M_ + (m0 + r)) * D_ + d0 + c * 16;
  #pragma unroll
  for (int i = 0; i < 4; ++i) {
    float4 v = reinterpret_cast<const float4*>(src)[i];
    t[r][c * 16 + i * 4 + 0] = v.x;
    t[r][c * 16 + i * 4 + 1] = v.y;
    t[r][c * 16 + i * 4 + 2] = v.z;
    t[r][c * 16 + i * 4 + 3] = v.w;
  }
  __syncthreads();
  const float* cs = colsum + (size_t)b * M_ + m0 + c * 16;
  ushort4 ob[4];
  #pragma unroll
  for (int i = 0; i < 4; ++i) {
    float4 s4 = reinterpret_cast<const float4*>(cs)[i];
    float sx = 0x1p-16f / s4.x, sy = 0x1p-16f / s4.y;
    float sz = 0x1p-16f / s4.z, sw = 0x1p-16f / s4.w;
    ob[i].x = f2bf(t[c * 16 + i * 4 + 0][r] * sx);
    ob[i].y = f2bf(t[c * 16 + i * 4 + 1][r] * sy);
    ob[i].z = f2bf(t[c * 16 + i * 4 + 2][r] * sz);
    ob[i].w = f2bf(t[c * 16 + i * 4 + 3][r] * sw);
  }
  ushort4* dst = reinterpret_cast<ushort4*>(
      Vt + ((size_t)b * D_ + d0 + r) * M_ + m0 + c * 16);
  #pragma unroll
  for (int i = 0; i < 4; ++i) dst[i] = ob[i];
}

// ---------- pass 2: O[n,d] = sum_m 2^s2 * V'[d,m] ----------
// grid (N/128, B) = 512; 4 waves x 32n; m-chunks of 64 (64 MFMA per barrier-pair,
// 32 iters). All LDS addresses hoisted to loop-invariant base + constant offset;
// DMA via running pointers. Two-barrier single-buffer staging (replay-proven).
__global__ __launch_bounds__(256, 2) void attn_v4_kernel(
    const unsigned short* __restrict__ Qb, const unsigned short* __restrict__ Kb,
    const unsigned short* __restrict__ Vt, float* __restrict__ out) {
  const int b    = blockIdx.y;
  const int wv   = threadIdx.x >> 6;   // 0..3
  const int lane = threadIdx.x & 63;
  const int l15  = lane & 15;
  const int quad = lane >> 4;
  const int nq   = blockIdx.x * 128 + wv * 32;

  __shared__ unsigned short kbuf[64 * 128];    // 16 KB: rows m (256B, 16 chunks), pos c^(m&15)
  __shared__ unsigned short vbuf[128 * 64];    // 16 KB: rows d (128B, 8 chunks),  pos c^(d&7)
  __shared__ unsigned short pbuf[4][32 * 68];  // 17 KB: per-wave P^T [n][m], stride 136B

  // Q B-operand: B[col=n=ng*16+l15][k=quad*8+j] — loop invariant
  bf16x8 qf[2][4];
  #pragma unroll
  for (int ng = 0; ng < 2; ++ng) {
    const unsigned short* Qr =
        Qb + ((size_t)b * N_ + nq + ng * 16 + l15) * D_ + quad * 8;
    #pragma unroll
    for (int kc = 0; kc < 4; ++kc)
      qf[ng][kc] = *reinterpret_cast<const bf16x8*>(Qr + kc * 32);
  }

  // hoisted LDS bases
  const unsigned short* pk[4];   // K read: + cg*4096 B
  #pragma unroll
  for (int kc = 0; kc < 4; ++kc)
    pk[kc] = kbuf + l15 * 128 + (((kc * 4 + quad) ^ l15) * 8);
  const unsigned short* pv[2];   // V read: + dt*2048 B
  #pragma unroll
  for (int kc2 = 0; kc2 < 2; ++kc2)
    pv[kc2] = vbuf + l15 * 64 + (((kc2 * 4 + quad) ^ (l15 & 7)) * 8);
  unsigned short* pww[2];        // P write: + cg*32 B
  const unsigned short* pwr[2];  // P read:  + kc2*64 B
  #pragma unroll
  for (int ng = 0; ng < 2; ++ng) {
    pww[ng] = pbuf[wv] + (ng * 16 + l15) * 68 + quad * 4;
    pwr[ng] = pbuf[wv] + (ng * 16 + l15) * 68 + quad * 8;
  }

  // running DMA source ptrs (4 K + 4 V slots per thread), constant LDS dests
  const unsigned short* kg[4]; unsigned short* kl[4];
  const unsigned short* vg[4]; unsigned short* vl[4];
  #pragma unroll
  for (int i = 0; i < 4; ++i) {
    int s = i * 256 + threadIdx.x;               // 16B slot 0..1023
    int mloc = s >> 4, ck = (s & 15) ^ (mloc & 15);
    kg[i] = Kb + ((size_t)b * M_ + mloc) * D_ + ck * 8;
    kl[i] = kbuf + (size_t)s * 8;
    int dloc = s >> 3, cv = (s & 7) ^ (dloc & 7);
    vg[i] = Vt + ((size_t)b * D_ + dloc) * M_ + cv * 8;
    vl[i] = vbuf + (size_t)s * 8;
  }

  f32x4 o[2][8];
  #pragma unroll
  for (int ng = 0; ng < 2; ++ng)
    #pragma unroll
    for (int dt = 0; dt < 8; ++dt) o[ng][dt] = (f32x4){0.f, 0.f, 0.f, 0.f};

  for (int it = 0; it < M_ / 64; ++it) {
    __syncthreads();                             // previous-chunk reads done
    #pragma unroll
    for (int i = 0; i < 4; ++i) {
      gl2lds16(kg[i], kl[i]);  kg[i] += 64 * D_;   // next 64 m-rows
      gl2lds16(vg[i], vl[i]);  vg[i] += 64;        // next 64 m-cols
    }
    __syncthreads();                             // staging visible

    // QK^T (S^T): sacc[cg][ng]: row m = cg*16+quad*4+r, col n = ng*16+l15
    f32x4 sacc[4][2];
    #pragma unroll
    for (int cg = 0; cg < 4; ++cg)
      #pragma unroll
      for (int ng = 0; ng < 2; ++ng) sacc[cg][ng] = (f32x4){0.f,0.f,0.f,0.f};
    #pragma unroll
    for (int kc = 0; kc < 4; ++kc)
      #pragma unroll
      for (int cg = 0; cg < 4; ++cg) {
        bf16x8 kfr = *reinterpret_cast<const bf16x8*>(pk[kc] + cg * 2048);
        sacc[cg][0] = __builtin_amdgcn_mfma_f32_16x16x32_bf16(kfr, qf[0][kc], sacc[cg][0], 0, 0, 0);
        sacc[cg][1] = __builtin_amdgcn_mfma_f32_16x16x32_bf16(kfr, qf[1][kc], sacc[cg][1], 0, 0, 0);
      }
    // P stores: packed b64 of 4 consecutive m per (cg, ng)
    #pragma unroll
    for (int cg = 0; cg < 4; ++cg)
      #pragma unroll
      for (int ng = 0; ng < 2; ++ng) {
        uint2 w;
        w.x = pk2bf(fexp2(sacc[cg][ng][0]), fexp2(sacc[cg][ng][1]));
        w.y = pk2bf(fexp2(sacc[cg][ng][2]), fexp2(sacc[cg][ng][3]));
        *reinterpret_cast<uint2*>(pww[ng] + cg * 16) = w;
      }
    // P A-frags (same-wave LDS RAW; lgkmcnt ordered): A[row=n][k=m=kc2*32+quad*8+j]
    bf16x8 pa[2][2];
    #pragma unroll
    for (int ng = 0; ng < 2; ++ng)
      #pragma unroll
      for (int kc2 = 0; kc2 < 2; ++kc2)
        pa[ng][kc2] = *reinterpret_cast<const bf16x8*>(pwr[ng] + kc2 * 32);
    // PV: each V-frag read feeds both n-groups
    #pragma unroll
    for (int dt = 0; dt < 8; ++dt)
      #pragma unroll
      for (int kc2 = 0; kc2 < 2; ++kc2) {
        bf16x8 vfr = *reinterpret_cast<const bf16x8*>(pv[kc2] + dt * 1024);
        o[0][dt] = __builtin_amdgcn_mfma_f32_16x16x32_bf16(pa[0][kc2], vfr, o[0][dt], 0, 0, 0);
        o[1][dt] = __builtin_amdgcn_mfma_f32_16x16x32_bf16(pa[1][kc2], vfr, o[1][dt], 0, 0, 0);
      }
  }

  // epilogue: o[ng][dt][r] = O[nq + ng*16 + quad*4 + r][dt*16 + l15]
  #pragma unroll
  for (int ng = 0; ng < 2; ++ng)
    #pragma unroll
    for (int dt = 0; dt < 8; ++dt)
      #pragma unroll
      for (int r = 0; r < 4; ++r)
        out[((size_t)b * N_ + nq + ng * 16 + quad * 4 + r) * D_ + dt * 16 + l15] =
            o[ng][dt][r];
}

extern "C" void kernel_launch(void* const* d_in, const int* in_sizes, int n_in,
                              void* d_out, int out_size, void* d_ws, size_t ws_size,
                              hipStream_t stream) {
  const float* Q = (const float*)d_in[0];
  const float* K = (const float*)d_in[1];
  const float* V = (const float*)d_in[2];
  float* out = (float*)d_out;

  const size_t elems = (size_t)B_ * N_ * D_;   // 8,388,608 per tensor
  unsigned short* Qb = (unsigned short*)d_ws;                  // 16 MB
  unsigned short* Kb = Qb + elems;                             // 16 MB
  unsigned short* Vt = Kb + elems;                             // 16 MB
  float* colsum = (float*)(Vt + elems);                        // 256 KB
  // total ws use ~= 48.3 MB (proven safe)

  const int n4 = (int)(elems / 4);
  cvt_qk_kernel<<<dim3(n4 / 256, 2), 256, 0, stream>>>(Q, K, Qb, Kb, colsum, n4);
  colstats_v4_kernel<<<dim3(M_ / 64, 4, B_), 128, 0, stream>>>(Qb, Kb, colsum);
  transpose_v_kernel<<<dim3(M_ / 64, D_ / 64, B_), 256, 0, stream>>>(V, colsum, Vt);
  attn_v4_kernel<<<dim3(N_ / 128, B_), 256, 0, stream>>>(Qb, Kb, Vt, out);
}

// Round 10
// 253.303 us; speedup vs baseline: 1.2785x; 1.0496x over previous
//
#include <hip/hip_runtime.h>
#include <hip/hip_bf16.h>

#define B_  32
#define N_  2048
#define M_  2048
#define D_  128

typedef __attribute__((ext_vector_type(4)))  float f32x4;
typedef __attribute__((ext_vector_type(8)))  short bf16x8;

// log2(e) / sqrt(128): softmax in exp2 domain; folded into Q's bf16 cast.
static constexpr float SCALE2 = 1.4426950408889634f / 11.313708498984761f;

__device__ __forceinline__ unsigned short f2bf(float x) {
  union { float f; unsigned u; } c; c.f = x;
  unsigned u = c.u;
  return (unsigned short)((u + 0x7FFFu + ((u >> 16) & 1u)) >> 16);  // RNE
}

__device__ __forceinline__ unsigned pk2bf(float a, float b) {
  float2 f2; f2.x = a; f2.y = b;
  __hip_bfloat162 h = __float22bfloat162_rn(f2);   // v_cvt_pk_bf16_f32
  union { __hip_bfloat162 h; unsigned u; } c; c.h = h;
  return c.u;
}

// raw v_exp_f32 (2^x) — skips ocml edge-case wrapper VALU
__device__ __forceinline__ float fexp2(float x) {
#if __has_builtin(__builtin_amdgcn_exp2f)
  return __builtin_amdgcn_exp2f(x);
#else
  float r; asm("v_exp_f32 %0, %1" : "=v"(r) : "v"(x)); return r;
#endif
}

// async global->LDS, 16B per lane; LDS dest = wave-uniform base + lane*16
__device__ __forceinline__ void gl2lds16(const void* gp, void* lp) {
  __builtin_amdgcn_global_load_lds(
      (const __attribute__((address_space(1))) unsigned int*)gp,
      (__attribute__((address_space(3))) unsigned int*)lp, 16, 0, 0);
}

// ---------- prep: fp32 -> bf16 for Q (scale=SCALE2) / K (scale=1); zero colsum ----------
__global__ __launch_bounds__(256) void cvt_qk_kernel(
    const float* __restrict__ Q, const float* __restrict__ K,
    unsigned short* __restrict__ Qb, unsigned short* __restrict__ Kb,
    float* __restrict__ colsum, int n4) {
  int i = blockIdx.x * 256 + threadIdx.x;
  if (i >= n4) return;
  if (blockIdx.y == 0 && i < (B_ * M_) / 4)
    reinterpret_cast<float4*>(colsum)[i] = make_float4(0.f, 0.f, 0.f, 0.f);
  const float* src = blockIdx.y ? K : Q;
  unsigned short* dst = blockIdx.y ? Kb : Qb;
  const float sc = blockIdx.y ? 1.0f : SCALE2;
  const float4 v = reinterpret_cast<const float4*>(src)[i];
  ushort4 o;
  o.x = f2bf(v.x * sc); o.y = f2bf(v.y * sc);
  o.z = f2bf(v.z * sc); o.w = f2bf(v.w * sc);
  reinterpret_cast<ushort4*>(dst)[i] = o;
}

// ---------- pass 1: colsum[b][m] += sum_{n in stripe} 2^(s2[n,m]-16) ----------
// grid (M/128, 4 n-stripes, B) = 2048 blocks x 4 waves (8 blocks/CU, 32 waves/CU).
// Wave owns 32 m (K-frags in regs); 16 KB Q-stage shared by 4 waves.
__global__ __launch_bounds__(256, 4) void colstats_v5_kernel(
    const unsigned short* __restrict__ Qb, const unsigned short* __restrict__ Kb,
    float* __restrict__ colsum) {
  const int b    = blockIdx.z;
  const int lane = threadIdx.x & 63;
  const int l15  = lane & 15;
  const int quad = lane >> 4;
  const int mw   = blockIdx.x * 128 + (threadIdx.x >> 6) * 32;
  const int nbase = blockIdx.y * (N_ / 4);

  __shared__ unsigned short qbuf[64 * 128];   // 16 KB; rows n (256B, 16 chunks), pos c^(n&15)

  bf16x8 kf[2][4];   // B-operand: B[col=m=cg*16+l15][k=quad*8+j]
  #pragma unroll
  for (int cg = 0; cg < 2; ++cg) {
    const unsigned short* Kr =
        Kb + ((size_t)b * M_ + mw + cg * 16 + l15) * D_ + quad * 8;
    #pragma unroll
    for (int kc = 0; kc < 4; ++kc)
      kf[cg][kc] = *reinterpret_cast<const bf16x8*>(Kr + kc * 32);
  }

  // hoisted LDS read bases: addr = pq[kc] + ng*2048 (u16)
  const unsigned short* pq[4];
  #pragma unroll
  for (int kc = 0; kc < 4; ++kc)
    pq[kc] = qbuf + l15 * 128 + (((kc * 4 + quad) ^ l15) * 8);

  // running DMA source pointers (4 slots/thread), constant LDS dests
  const unsigned short* qg[4];
  unsigned short* ql[4];
  #pragma unroll
  for (int i = 0; i < 4; ++i) {
    int s = i * 256 + threadIdx.x;              // 16B slot 0..1023
    int nloc = s >> 4, c = (s & 15) ^ (nloc & 15);
    qg[i] = Qb + ((size_t)b * N_ + nbase + nloc) * D_ + c * 8;
    ql[i] = qbuf + (size_t)s * 8;               // s*16 bytes
  }

  float psum[2] = {0.f, 0.f};

  for (int it = 0; it < (N_ / 4) / 64; ++it) {
    __syncthreads();                            // previous-tile reads done
    #pragma unroll
    for (int i = 0; i < 4; ++i) {
      gl2lds16(qg[i], ql[i]);
      qg[i] += 64 * D_;
    }
    __syncthreads();                            // staging visible
    #pragma unroll
    for (int ng = 0; ng < 4; ++ng) {
      f32x4 acc[2] = {{0.f,0.f,0.f,0.f}, {0.f,0.f,0.f,0.f}};
      #pragma unroll
      for (int kc = 0; kc < 4; ++kc) {
        bf16x8 af = *reinterpret_cast<const bf16x8*>(pq[kc] + ng * 2048);
        acc[0] = __builtin_amdgcn_mfma_f32_16x16x32_bf16(af, kf[0][kc], acc[0], 0, 0, 0);
        acc[1] = __builtin_amdgcn_mfma_f32_16x16x32_bf16(af, kf[1][kc], acc[1], 0, 0, 0);
      }
      #pragma unroll
      for (int cg = 0; cg < 2; ++cg)
        psum[cg] += fexp2(acc[cg][0] - 16.f) + fexp2(acc[cg][1] - 16.f) +
                    fexp2(acc[cg][2] - 16.f) + fexp2(acc[cg][3] - 16.f);
    }
  }
  #pragma unroll
  for (int cg = 0; cg < 2; ++cg) {
    psum[cg] += __shfl_xor(psum[cg], 16);
    psum[cg] += __shfl_xor(psum[cg], 32);
  }
  if (quad == 0) {
    atomicAdd(colsum + (size_t)b * M_ + mw + l15,      psum[0]);
    atomicAdd(colsum + (size_t)b * M_ + mw + 16 + l15, psum[1]);
  }
}

// ---------- prep: V (b,m,d) fp32 -> Vt (b,d,m) bf16, folding 2^-16/colsum[m] ----------
__global__ __launch_bounds__(256) void transpose_v_kernel(
    const float* __restrict__ V, const float* __restrict__ colsum,
    unsigned short* __restrict__ Vt) {
  const int b = blockIdx.z;
  const int m0 = blockIdx.x * 64;
  const int d0 = blockIdx.y * 64;
  __shared__ float t[64][65];
  const int tid = threadIdx.x;
  const int r = tid >> 2;   // 0..63
  const int c = tid & 3;    // 0..3
  const float* src = V + ((size_t)b * M_ + (m0 + r)) * D_ + d0 + c * 16;
  #pragma unroll
  for (int i = 0; i < 4; ++i) {
    float4 v = reinterpret_cast<const float4*>(src)[i];
    t[r][c * 16 + i * 4 + 0] = v.x;
    t[r][c * 16 + i * 4 + 1] = v.y;
    t[r][c * 16 + i * 4 + 2] = v.z;
    t[r][c * 16 + i * 4 + 3] = v.w;
  }
  __syncthreads();
  const float* cs = colsum + (size_t)b * M_ + m0 + c * 16;
  ushort4 ob[4];
  #pragma unroll
  for (int i = 0; i < 4; ++i) {
    float4 s4 = reinterpret_cast<const float4*>(cs)[i];
    float sx = 0x1p-16f / s4.x, sy = 0x1p-16f / s4.y;
    float sz = 0x1p-16f / s4.z, sw = 0x1p-16f / s4.w;
    ob[i].x = f2bf(t[c * 16 + i * 4 + 0][r] * sx);
    ob[i].y = f2bf(t[c * 16 + i * 4 + 1][r] * sy);
    ob[i].z = f2bf(t[c * 16 + i * 4 + 2][r] * sz);
    ob[i].w = f2bf(t[c * 16 + i * 4 + 3][r] * sw);
  }
  ushort4* dst = reinterpret_cast<ushort4*>(
      Vt + ((size_t)b * D_ + d0 + r) * M_ + m0 + c * 16);
  #pragma unroll
  for (int i = 0; i < 4; ++i) dst[i] = ob[i];
}

// ---------- pass 2: O[n,d] = sum_m 2^s2 * V'[d,m] ----------
// grid (N/128, B) = 512; 4 waves x 32n; m-chunks of 128 (16 iters -> half the
// barrier/drain events of R9), P in 4 independent 32m sub-chunks per iter
// (QK->exp->P->PV chains interleave for in-wave ILP). Hoisted addresses,
// running DMA pointers, two-barrier single-buffer staging (replay-proven).
__global__ __launch_bounds__(256, 2) void attn_v5_kernel(
    const unsigned short* __restrict__ Qb, const unsigned short* __restrict__ Kb,
    const unsigned short* __restrict__ Vt, float* __restrict__ out) {
  const int b    = blockIdx.y;
  const int wv   = threadIdx.x >> 6;   // 0..3
  const int lane = threadIdx.x & 63;
  const int l15  = lane & 15;
  const int quad = lane >> 4;
  const int nq   = blockIdx.x * 128 + wv * 32;

  __shared__ unsigned short kbuf[128 * 128];   // 32 KB: rows m (256B, 16 chunks), pos c^(m&15)
  __shared__ unsigned short vbuf[128 * 128];   // 32 KB: rows d (256B, 16 chunks), pos c^(d&15)
  __shared__ unsigned short pbuf[4][32 * 40];  // 10 KB: per-wave P^T [n][m32], stride 80B

  // Q B-operand: B[col=n=ng*16+l15][k=quad*8+j] — loop invariant
  bf16x8 qf[2][4];
  #pragma unroll
  for (int ng = 0; ng < 2; ++ng) {
    const unsigned short* Qr =
        Qb + ((size_t)b * N_ + nq + ng * 16 + l15) * D_ + quad * 8;
    #pragma unroll
    for (int kc = 0; kc < 4; ++kc)
      qf[ng][kc] = *reinterpret_cast<const bf16x8*>(Qr + kc * 32);
  }

  // hoisted LDS bases (u16 units)
  const unsigned short* pk[4];   // K read: + sub*4096 + cg*2048
  #pragma unroll
  for (int kc = 0; kc < 4; ++kc)
    pk[kc] = kbuf + l15 * 128 + (((kc * 4 + quad) ^ l15) * 8);
  const unsigned short* pv[4];   // V read: + dt*2048
  #pragma unroll
  for (int sub = 0; sub < 4; ++sub)
    pv[sub] = vbuf + l15 * 128 + (((sub * 4 + quad) ^ l15) * 8);
  unsigned short* pww[2];        // P write: + cg*16
  const unsigned short* pwr[2];  // P read
  #pragma unroll
  for (int ng = 0; ng < 2; ++ng) {
    pww[ng] = pbuf[wv] + (ng * 16 + l15) * 40 + quad * 4;
    pwr[ng] = pbuf[wv] + (ng * 16 + l15) * 40 + quad * 8;
  }

  // running DMA source ptrs (8 K + 8 V slots per thread), constant LDS dests
  const unsigned short* kg[8]; unsigned short* kl[8];
  const unsigned short* vg[8]; unsigned short* vl[8];
  #pragma unroll
  for (int i = 0; i < 8; ++i) {
    int s = i * 256 + threadIdx.x;               // 16B slot 0..2047
    int row = s >> 4, c = (s & 15) ^ (row & 15);
    kg[i] = Kb + ((size_t)b * M_ + row) * D_ + c * 8;
    kl[i] = kbuf + (size_t)s * 8;
    vg[i] = Vt + ((size_t)b * D_ + row) * M_ + c * 8;
    vl[i] = vbuf + (size_t)s * 8;
  }

  f32x4 o[2][8];
  #pragma unroll
  for (int ng = 0; ng < 2; ++ng)
    #pragma unroll
    for (int dt = 0; dt < 8; ++dt) o[ng][dt] = (f32x4){0.f, 0.f, 0.f, 0.f};

  for (int it = 0; it < M_ / 128; ++it) {
    __syncthreads();                             // previous-chunk reads done
    #pragma unroll
    for (int i = 0; i < 8; ++i) {
      gl2lds16(kg[i], kl[i]);  kg[i] += 128 * D_;   // next 128 m-rows
      gl2lds16(vg[i], vl[i]);  vg[i] += 128;        // next 128 m-cols
    }
    __syncthreads();                             // staging visible

    #pragma unroll
    for (int sub = 0; sub < 4; ++sub) {
      // QK^T (S^T): sacc[cg][ng]: row m = sub*32+cg*16+quad*4+r, col n = ng*16+l15
      f32x4 sacc[2][2] = {{{0.f,0.f,0.f,0.f},{0.f,0.f,0.f,0.f}},
                          {{0.f,0.f,0.f,0.f},{0.f,0.f,0.f,0.f}}};
      #pragma unroll
      for (int kc = 0; kc < 4; ++kc)
        #pragma unroll
        for (int cg = 0; cg < 2; ++cg) {
          bf16x8 kfr = *reinterpret_cast<const bf16x8*>(pk[kc] + sub * 4096 + cg * 2048);
          sacc[cg][0] = __builtin_amdgcn_mfma_f32_16x16x32_bf16(kfr, qf[0][kc], sacc[cg][0], 0, 0, 0);
          sacc[cg][1] = __builtin_amdgcn_mfma_f32_16x16x32_bf16(kfr, qf[1][kc], sacc[cg][1], 0, 0, 0);
        }
      // P stores: packed b64 of 4 consecutive m per (cg, ng)
      #pragma unroll
      for (int cg = 0; cg < 2; ++cg)
        #pragma unroll
        for (int ng = 0; ng < 2; ++ng) {
          uint2 w;
          w.x = pk2bf(fexp2(sacc[cg][ng][0]), fexp2(sacc[cg][ng][1]));
          w.y = pk2bf(fexp2(sacc[cg][ng][2]), fexp2(sacc[cg][ng][3]));
          *reinterpret_cast<uint2*>(pww[ng] + cg * 16) = w;
        }
      // P A-frags (same-wave LDS RAW; lgkmcnt ordered): A[row=n][k=m32=quad*8+j]
      bf16x8 pa[2];
      #pragma unroll
      for (int ng = 0; ng < 2; ++ng)
        pa[ng] = *reinterpret_cast<const bf16x8*>(pwr[ng]);
      // PV: each V-frag read feeds both n-groups
      #pragma unroll
      for (int dt = 0; dt < 8; ++dt) {
        bf16x8 vfr = *reinterpret_cast<const bf16x8*>(pv[sub] + dt * 2048);
        o[0][dt] = __builtin_amdgcn_mfma_f32_16x16x32_bf16(pa[0], vfr, o[0][dt], 0, 0, 0);
        o[1][dt] = __builtin_amdgcn_mfma_f32_16x16x32_bf16(pa[1], vfr, o[1][dt], 0, 0, 0);
      }
    }
  }

  // epilogue: o[ng][dt][r] = O[nq + ng*16 + quad*4 + r][dt*16 + l15]
  #pragma unroll
  for (int ng = 0; ng < 2; ++ng)
    #pragma unroll
    for (int dt = 0; dt < 8; ++dt)
      #pragma unroll
      for (int r = 0; r < 4; ++r)
        out[((size_t)b * N_ + nq + ng * 16 + quad * 4 + r) * D_ + dt * 16 + l15] =
            o[ng][dt][r];
}

extern "C" void kernel_launch(void* const* d_in, const int* in_sizes, int n_in,
                              void* d_out, int out_size, void* d_ws, size_t ws_size,
                              hipStream_t stream) {
  const float* Q = (const float*)d_in[0];
  const float* K = (const float*)d_in[1];
  const float* V = (const float*)d_in[2];
  float* out = (float*)d_out;

  const size_t elems = (size_t)B_ * N_ * D_;   // 8,388,608 per tensor
  unsigned short* Qb = (unsigned short*)d_ws;                  // 16 MB
  unsigned short* Kb = Qb + elems;                             // 16 MB
  unsigned short* Vt = Kb + elems;                             // 16 MB
  float* colsum = (float*)(Vt + elems);                        // 256 KB
  // total ws use ~= 48.3 MB (proven safe)

  const int n4 = (int)(elems / 4);
  cvt_qk_kernel<<<dim3(n4 / 256, 2), 256, 0, stream>>>(Q, K, Qb, Kb, colsum, n4);
  colstats_v5_kernel<<<dim3(M_ / 128, 4, B_), 256, 0, stream>>>(Qb, Kb, colsum);
  transpose_v_kernel<<<dim3(M_ / 64, D_ / 64, B_), 256, 0, stream>>>(V, colsum, Vt);
  attn_v5_kernel<<<dim3(N_ / 128, B_), 256, 0, stream>>>(Qb, Kb, Vt, out);
}

// Round 11
// 241.389 us; speedup vs baseline: 1.3416x; 1.0494x over previous
//
#include <hip/hip_runtime.h>
#include <hip/hip_bf16.h>

#define B_  32
#define N_  2048
#define M_  2048
#define D_  128

typedef __attribute__((ext_vector_type(4)))  float f32x4;
typedef __attribute__((ext_vector_type(8)))  short bf16x8;

// log2(e) / sqrt(128): softmax in exp2 domain; folded into Q's bf16 cast.
static constexpr float SCALE2 = 1.4426950408889634f / 11.313708498984761f;

__device__ __forceinline__ unsigned short f2bf(float x) {
  union { float f; unsigned u; } c; c.f = x;
  unsigned u = c.u;
  return (unsigned short)((u + 0x7FFFu + ((u >> 16) & 1u)) >> 16);  // RNE
}

__device__ __forceinline__ unsigned pk2bf(float a, float b) {
  float2 f2; f2.x = a; f2.y = b;
  __hip_bfloat162 h = __float22bfloat162_rn(f2);   // v_cvt_pk_bf16_f32
  union { __hip_bfloat162 h; unsigned u; } c; c.h = h;
  return c.u;
}

// raw v_exp_f32 (2^x) / v_log_f32 (log2 x) — skip ocml wrapper VALU
__device__ __forceinline__ float fexp2(float x) {
#if __has_builtin(__builtin_amdgcn_exp2f)
  return __builtin_amdgcn_exp2f(x);
#else
  float r; asm("v_exp_f32 %0, %1" : "=v"(r) : "v"(x)); return r;
#endif
}
__device__ __forceinline__ float flog2(float x) {
#if __has_builtin(__builtin_amdgcn_logf)
  return __builtin_amdgcn_logf(x);
#else
  float r; asm("v_log_f32 %0, %1" : "=v"(r) : "v"(x)); return r;
#endif
}

// async global->LDS, 16B per lane; LDS dest = wave-uniform base + lane*16
__device__ __forceinline__ void gl2lds16(const void* gp, void* lp) {
  __builtin_amdgcn_global_load_lds(
      (const __attribute__((address_space(1))) unsigned int*)gp,
      (__attribute__((address_space(3))) unsigned int*)lp, 16, 0, 0);
}

// ---------- prep (one dispatch): cast Q (SCALE2), cast K, transpose V, zero colsum ----------
// blocks [0,8192): Q cast; [8192,16384): K cast; [16384,18432): V transpose.
__global__ __launch_bounds__(256) void prep_kernel(
    const float* __restrict__ Q, const float* __restrict__ K,
    const float* __restrict__ V, unsigned short* __restrict__ Qb,
    unsigned short* __restrict__ Kb, unsigned short* __restrict__ Vt,
    float* __restrict__ colsum, int n4) {
  const int blk = blockIdx.x;
  if (blk < 16384) {
    int i = (blk & 8191) * 256 + threadIdx.x;
    if (i >= n4) return;
    if (blk < 64 && i < (B_ * M_) / 4)
      reinterpret_cast<float4*>(colsum)[i] = make_float4(0.f, 0.f, 0.f, 0.f);
    const bool isK = blk >= 8192;
    const float* src = isK ? K : Q;
    unsigned short* dst = isK ? Kb : Qb;
    const float sc = isK ? 1.0f : SCALE2;
    const float4 v = reinterpret_cast<const float4*>(src)[i];
    ushort4 o;
    o.x = f2bf(v.x * sc); o.y = f2bf(v.y * sc);
    o.z = f2bf(v.z * sc); o.w = f2bf(v.w * sc);
    reinterpret_cast<ushort4*>(dst)[i] = o;
    return;
  }
  // V transpose: idx -> (b, m0, d0); grid was (M/64=32, D/64=2, B=32) = 2048
  const int idx = blk - 16384;
  const int b  = idx >> 6;
  const int m0 = ((idx >> 1) & 31) * 64;
  const int d0 = (idx & 1) * 64;
  __shared__ float t[64][65];
  const int tid = threadIdx.x;
  const int r = tid >> 2;   // 0..63
  const int c = tid & 3;    // 0..3
  const float* src = V + ((size_t)b * M_ + (m0 + r)) * D_ + d0 + c * 16;
  #pragma unroll
  for (int i = 0; i < 4; ++i) {
    float4 v = reinterpret_cast<const float4*>(src)[i];
    t[r][c * 16 + i * 4 + 0] = v.x;
    t[r][c * 16 + i * 4 + 1] = v.y;
    t[r][c * 16 + i * 4 + 2] = v.z;
    t[r][c * 16 + i * 4 + 3] = v.w;
  }
  __syncthreads();
  ushort4 ob[4];
  #pragma unroll
  for (int i = 0; i < 4; ++i) {
    ob[i].x = f2bf(t[c * 16 + i * 4 + 0][r]);
    ob[i].y = f2bf(t[c * 16 + i * 4 + 1][r]);
    ob[i].z = f2bf(t[c * 16 + i * 4 + 2][r]);
    ob[i].w = f2bf(t[c * 16 + i * 4 + 3][r]);
  }
  ushort4* dst = reinterpret_cast<ushort4*>(
      Vt + ((size_t)b * D_ + d0 + r) * M_ + m0 + c * 16);
  #pragma unroll
  for (int i = 0; i < 4; ++i) dst[i] = ob[i];
}

// ---------- pass 1: colsum[b][m] += sum_{n in stripe} 2^(s2[n,m]-16) ----------
// grid (M/256, 8 stripes, B) = 2048 blocks x 4 waves. Wave owns 64 m (16 K-frags
// in regs) -> each Q-frag LDS read feeds 4 MFMA; 64 MFMA per barrier-pair; only
// 4 iters/block. Hoisted addresses, running DMA ptrs, two-barrier staging.
__global__ __launch_bounds__(256, 4) void colstats_v6_kernel(
    const unsigned short* __restrict__ Qb, const unsigned short* __restrict__ Kb,
    float* __restrict__ colsum) {
  const int b    = blockIdx.z;
  const int lane = threadIdx.x & 63;
  const int l15  = lane & 15;
  const int quad = lane >> 4;
  const int mw   = blockIdx.x * 256 + (threadIdx.x >> 6) * 64;
  const int nbase = blockIdx.y * (N_ / 8);   // 256-n stripe

  __shared__ unsigned short qbuf[64 * 128];  // 16 KB; rows n (256B, 16 chunks), pos c^(n&15)

  bf16x8 kf[4][4];   // B-operand: B[col=m=cg*16+l15][k=quad*8+j] — 64 VGPRs
  #pragma unroll
  for (int cg = 0; cg < 4; ++cg) {
    const unsigned short* Kr =
        Kb + ((size_t)b * M_ + mw + cg * 16 + l15) * D_ + quad * 8;
    #pragma unroll
    for (int kc = 0; kc < 4; ++kc)
      kf[cg][kc] = *reinterpret_cast<const bf16x8*>(Kr + kc * 32);
  }

  // hoisted LDS read bases: addr = pq[kc] + ng*2048 (u16)
  const unsigned short* pq[4];
  #pragma unroll
  for (int kc = 0; kc < 4; ++kc)
    pq[kc] = qbuf + l15 * 128 + (((kc * 4 + quad) ^ l15) * 8);

  // running DMA source pointers (4 slots/thread), constant LDS dests
  const unsigned short* qg[4];
  unsigned short* ql[4];
  #pragma unroll
  for (int i = 0; i < 4; ++i) {
    int s = i * 256 + threadIdx.x;             // 16B slot 0..1023
    int nloc = s >> 4, c = (s & 15) ^ (nloc & 15);
    qg[i] = Qb + ((size_t)b * N_ + nbase + nloc) * D_ + c * 8;
    ql[i] = qbuf + (size_t)s * 8;              // s*16 bytes
  }

  float psum[4] = {0.f, 0.f, 0.f, 0.f};

  for (int it = 0; it < 4; ++it) {
    __syncthreads();                           // previous-tile reads done
    #pragma unroll
    for (int i = 0; i < 4; ++i) {
      gl2lds16(qg[i], ql[i]);
      qg[i] += 64 * D_;
    }
    __syncthreads();                           // staging visible
    #pragma unroll
    for (int ng = 0; ng < 4; ++ng) {
      f32x4 acc[4] = {{0.f,0.f,0.f,0.f}, {0.f,0.f,0.f,0.f},
                      {0.f,0.f,0.f,0.f}, {0.f,0.f,0.f,0.f}};
      #pragma unroll
      for (int kc = 0; kc < 4; ++kc) {
        bf16x8 af = *reinterpret_cast<const bf16x8*>(pq[kc] + ng * 2048);
        #pragma unroll
        for (int cg = 0; cg < 4; ++cg)
          acc[cg] = __builtin_amdgcn_mfma_f32_16x16x32_bf16(af, kf[cg][kc], acc[cg], 0, 0, 0);
      }
      #pragma unroll
      for (int cg = 0; cg < 4; ++cg)
        psum[cg] += fexp2(acc[cg][0] - 16.f) + fexp2(acc[cg][1] - 16.f) +
                    fexp2(acc[cg][2] - 16.f) + fexp2(acc[cg][3] - 16.f);
    }
  }
  #pragma unroll
  for (int cg = 0; cg < 4; ++cg) {
    psum[cg] += __shfl_xor(psum[cg], 16);
    psum[cg] += __shfl_xor(psum[cg], 32);
  }
  if (quad == 0) {
    #pragma unroll
    for (int cg = 0; cg < 4; ++cg)
      atomicAdd(colsum + (size_t)b * M_ + mw + cg * 16 + l15, psum[cg]);
  }
}

// ---------- pass 2: O[n,d] = sum_m 2^(s2[n,m]-cml[m]) * Vt[d,m] ----------
// grid (N/128, B) = 512; 4 waves x 32n; m-chunks of 128; normalization folded
// into the exp argument via cml[m] = 16 + log2(colsum[m]) (staged per chunk,
// v_log_f32, broadcast float4 reads). Otherwise identical to R10's attn_v5.
__global__ __launch_bounds__(256, 2) void attn_v6_kernel(
    const unsigned short* __restrict__ Qb, const unsigned short* __restrict__ Kb,
    const unsigned short* __restrict__ Vt, const float* __restrict__ colsum,
    float* __restrict__ out) {
  const int b    = blockIdx.y;
  const int wv   = threadIdx.x >> 6;   // 0..3
  const int lane = threadIdx.x & 63;
  const int l15  = lane & 15;
  const int quad = lane >> 4;
  const int nq   = blockIdx.x * 128 + wv * 32;

  __shared__ unsigned short kbuf[128 * 128];   // 32 KB: rows m (256B, 16 chunks), pos c^(m&15)
  __shared__ unsigned short vbuf[128 * 128];   // 32 KB: rows d (256B, 16 chunks), pos c^(d&15)
  __shared__ unsigned short pbuf[4][32 * 40];  // 10 KB: per-wave P^T [n][m32], stride 80B
  __shared__ float cmlb[128];                  // per-chunk log2 column denominators

  // Q B-operand: B[col=n=ng*16+l15][k=quad*8+j] — loop invariant
  bf16x8 qf[2][4];
  #pragma unroll
  for (int ng = 0; ng < 2; ++ng) {
    const unsigned short* Qr =
        Qb + ((size_t)b * N_ + nq + ng * 16 + l15) * D_ + quad * 8;
    #pragma unroll
    for (int kc = 0; kc < 4; ++kc)
      qf[ng][kc] = *reinterpret_cast<const bf16x8*>(Qr + kc * 32);
  }

  // hoisted LDS bases (u16 units)
  const unsigned short* pk[4];   // K read: + sub*4096 + cg*2048
  #pragma unroll
  for (int kc = 0; kc < 4; ++kc)
    pk[kc] = kbuf + l15 * 128 + (((kc * 4 + quad) ^ l15) * 8);
  const unsigned short* pv[4];   // V read: + dt*2048
  #pragma unroll
  for (int sub = 0; sub < 4; ++sub)
    pv[sub] = vbuf + l15 * 128 + (((sub * 4 + quad) ^ l15) * 8);
  unsigned short* pww[2];        // P write: + cg*16
  const unsigned short* pwr[2];  // P read
  #pragma unroll
  for (int ng = 0; ng < 2; ++ng) {
    pww[ng] = pbuf[wv] + (ng * 16 + l15) * 40 + quad * 4;
    pwr[ng] = pbuf[wv] + (ng * 16 + l15) * 40 + quad * 8;
  }

  // running DMA source ptrs (8 K + 8 V slots per thread), constant LDS dests
  const unsigned short* kg[8]; unsigned short* kl[8];
  const unsigned short* vg[8]; unsigned short* vl[8];
  #pragma unroll
  for (int i = 0; i < 8; ++i) {
    int s = i * 256 + threadIdx.x;               // 16B slot 0..2047
    int row = s >> 4, c = (s & 15) ^ (row & 15);
    kg[i] = Kb + ((size_t)b * M_ + row) * D_ + c * 8;
    kl[i] = kbuf + (size_t)s * 8;
    vg[i] = Vt + ((size_t)b * D_ + row) * M_ + c * 8;
    vl[i] = vbuf + (size_t)s * 8;
  }

  const float* csb = colsum + (size_t)b * M_;

  f32x4 o[2][8];
  #pragma unroll
  for (int ng = 0; ng < 2; ++ng)
    #pragma unroll
    for (int dt = 0; dt < 8; ++dt) o[ng][dt] = (f32x4){0.f, 0.f, 0.f, 0.f};

  for (int it = 0; it < M_ / 128; ++it) {
    __syncthreads();                             // previous-chunk reads done
    #pragma unroll
    for (int i = 0; i < 8; ++i) {
      gl2lds16(kg[i], kl[i]);  kg[i] += 128 * D_;   // next 128 m-rows
      gl2lds16(vg[i], vl[i]);  vg[i] += 128;        // next 128 m-cols
    }
    if (threadIdx.x < 128)
      cmlb[threadIdx.x] = flog2(csb[it * 128 + threadIdx.x]) + 16.f;
    __syncthreads();                             // staging + cml visible

    #pragma unroll
    for (int sub = 0; sub < 4; ++sub) {
      // QK^T (S^T): sacc[cg][ng]: row m = sub*32+cg*16+quad*4+r, col n = ng*16+l15
      f32x4 sacc[2][2] = {{{0.f,0.f,0.f,0.f},{0.f,0.f,0.f,0.f}},
                          {{0.f,0.f,0.f,0.f},{0.f,0.f,0.f,0.f}}};
      #pragma unroll
      for (int kc = 0; kc < 4; ++kc)
        #pragma unroll
        for (int cg = 0; cg < 2; ++cg) {
          bf16x8 kfr = *reinterpret_cast<const bf16x8*>(pk[kc] + sub * 4096 + cg * 2048);
          sacc[cg][0] = __builtin_amdgcn_mfma_f32_16x16x32_bf16(kfr, qf[0][kc], sacc[cg][0], 0, 0, 0);
          sacc[cg][1] = __builtin_amdgcn_mfma_f32_16x16x32_bf16(kfr, qf[1][kc], sacc[cg][1], 0, 0, 0);
        }
      // normalized P stores: w = 2^(s2 - cml[m]); packed b64 of 4 consecutive m
      #pragma unroll
      for (int cg = 0; cg < 2; ++cg) {
        float4 cm4 = *reinterpret_cast<const float4*>(
            cmlb + sub * 32 + cg * 16 + quad * 4);   // broadcast within quad
        #pragma unroll
        for (int ng = 0; ng < 2; ++ng) {
          uint2 w;
          w.x = pk2bf(fexp2(sacc[cg][ng][0] - cm4.x), fexp2(sacc[cg][ng][1] - cm4.y));
          w.y = pk2bf(fexp2(sacc[cg][ng][2] - cm4.z), fexp2(sacc[cg][ng][3] - cm4.w));
          *reinterpret_cast<uint2*>(pww[ng] + cg * 16) = w;
        }
      }
      // P A-frags (same-wave LDS RAW; lgkmcnt ordered): A[row=n][k=m32=quad*8+j]
      bf16x8 pa[2];
      #pragma unroll
      for (int ng = 0; ng < 2; ++ng)
        pa[ng] = *reinterpret_cast<const bf16x8*>(pwr[ng]);
      // PV: each V-frag read feeds both n-groups
      #pragma unroll
      for (int dt = 0; dt < 8; ++dt) {
        bf16x8 vfr = *reinterpret_cast<const bf16x8*>(pv[sub] + dt * 2048);
        o[0][dt] = __builtin_amdgcn_mfma_f32_16x16x32_bf16(pa[0], vfr, o[0][dt], 0, 0, 0);
        o[1][dt] = __builtin_amdgcn_mfma_f32_16x16x32_bf16(pa[1], vfr, o[1][dt], 0, 0, 0);
      }
    }
  }

  // epilogue: o[ng][dt][r] = O[nq + ng*16 + quad*4 + r][dt*16 + l15]
  #pragma unroll
  for (int ng = 0; ng < 2; ++ng)
    #pragma unroll
    for (int dt = 0; dt < 8; ++dt)
      #pragma unroll
      for (int r = 0; r < 4; ++r)
        out[((size_t)b * N_ + nq + ng * 16 + quad * 4 + r) * D_ + dt * 16 + l15] =
            o[ng][dt][r];
}

extern "C" void kernel_launch(void* const* d_in, const int* in_sizes, int n_in,
                              void* d_out, int out_size, void* d_ws, size_t ws_size,
                              hipStream_t stream) {
  const float* Q = (const float*)d_in[0];
  const float* K = (const float*)d_in[1];
  const float* V = (const float*)d_in[2];
  float* out = (float*)d_out;

  const size_t elems = (size_t)B_ * N_ * D_;   // 8,388,608 per tensor
  unsigned short* Qb = (unsigned short*)d_ws;                  // 16 MB
  unsigned short* Kb = Qb + elems;                             // 16 MB
  unsigned short* Vt = Kb + elems;                             // 16 MB
  float* colsum = (float*)(Vt + elems);                        // 256 KB
  // total ws use ~= 48.3 MB (proven safe)

  const int n4 = (int)(elems / 4);
  prep_kernel<<<18432, 256, 0, stream>>>(Q, K, V, Qb, Kb, Vt, colsum, n4);
  colstats_v6_kernel<<<dim3(M_ / 256, 8, B_), 256, 0, stream>>>(Qb, Kb, colsum);
  attn_v6_kernel<<<dim3(N_ / 128, B_), 256, 0, stream>>>(Qb, Kb, Vt, colsum, out);
}